// Round 6
// baseline (153.520 us; speedup 1.0000x reference)
//
#include <hip/hip_runtime.h>
#include <math.h>

typedef _Float16 f16;
typedef __attribute__((ext_vector_type(2))) _Float16 f16x2;
typedef __attribute__((ext_vector_type(4))) _Float16 f16x4;
typedef __attribute__((ext_vector_type(8))) _Float16 f16x8;
typedef __attribute__((ext_vector_type(4))) float f32x4;

#define NBATCH 8
#define WSA_ELE 36864      // 32*1152 (w_off padded to 32 rows, k-major, frag-swizzled)
#define WSB_ELE 147456     // 128*1152 (w_def, k-major, frag-swizzled)
#define PREP_BLOCKS 720    // (WSA_ELE + WSB_ELE) / 256
// workspace byte offsets
#define OFF_WSB  73728
#define OFF_XT   368640

// dynamic LDS layout (bytes)
#define XWIN_BYTES 114688  // 7 rows * 64 px * 256 B, XOR-swizzled within each pixel
#define OFS_OFF    114688  // 576 * uint4  packed corner descriptors
#define WT_OFF     123904  // 576 * float4 modulated weights
#define AOFF_OFF   133120  // phase1-2: s_off floats (27*65); phase3: s_a[2][4096] f16
#define SMEM_BYTES 149504

__device__ __forceinline__ void gload_lds16(const f16* gsrc, f16* ldst) {
  // wave-uniform LDS base; HW adds lane*16
  __builtin_amdgcn_global_load_lds(
      (const __attribute__((address_space(1))) unsigned int*)gsrc,
      (__attribute__((address_space(3))) unsigned int*)ldst, 16, 0, 0);
}

// packed corner descriptor: bits 0-16 = pixel byte offset in window (pix*256),
// bits 20-21 = x&3 (quarter XOR key), bit 22 = (x>>2)&1 (c4 XOR key)
#define CORNER_ADDR(wd, c4n) \
  ((int)((wd) & 0x1FFFFu) + ((q ^ (int)(((wd) >> 20) & 3u)) << 4) + \
   ((((c4n) ^ (int)(((wd) >> 22) & 1u))) << 6))

// ---------------- merged prep (weights -> fp16 frag-swizzled) + transpose ----------------
__global__ __launch_bounds__(256) void prep_transpose_kernel(const float* __restrict__ w_off,
                                                             const float* __restrict__ w_def,
                                                             f16* __restrict__ wsA,
                                                             f16* __restrict__ wsB,
                                                             const float* __restrict__ x,
                                                             f16* __restrict__ xt) {
  __shared__ __align__(16) f16 s_t[128 * 68];   // pitch 68: 8B-aligned rows
  const int t = threadIdx.x;
  if (blockIdx.x < PREP_BLOCKS) {
    int i = blockIdx.x * 256 + t;
    if (i < WSA_ELE) {
      int j = i & 7, lane = (i >> 3) & 63, fm = i >> 9;
      int ch = fm >> 1, mt = fm & 1;
      int row = mt * 16 + (lane & 15);
      int kidx = ch * 32 + (lane >> 4) * 8 + j;
      int k = kidx >> 7, cc = kidx & 127;
      float v = (row < 27) ? w_off[row * 1152 + cc * 9 + k] : 0.0f;
      wsA[i] = (f16)v;
    } else {
      int e = i - WSA_ELE;
      int j = e & 7, lane = (e >> 3) & 63, fm = e >> 9;
      int ch = fm >> 3, mt = fm & 7;
      int row = mt * 16 + (lane & 15);
      int kidx = ch * 32 + (lane >> 4) * 8 + j;
      int k = kidx >> 7, cc = kidx & 127;
      wsB[e] = (f16)w_def[row * 1152 + cc * 9 + k];
    }
    return;
  }
  const int bid = blockIdx.x - PREP_BLOCKS;
  const int b = bid >> 6;
  const int pos0 = (bid & 63) << 6;
  const float* xb = x + ((size_t)b << 19);
  #pragma unroll
  for (int it = 0; it < 8; ++it) {
    int i = it * 256 + t;
    int c = i >> 4, p4 = (i & 15) << 2;
    float4 v = *(const float4*)&xb[c * 4096 + pos0 + p4];
    f16x4 h = {(f16)v.x, (f16)v.y, (f16)v.z, (f16)v.w};
    *(f16x4*)&s_t[c * 68 + p4] = h;
  }
  __syncthreads();
  f16* xtb = xt + ((size_t)b << 19);
  #pragma unroll
  for (int it = 0; it < 8; ++it) {
    int i = it * 256 + t;
    int p = i >> 5, c4 = (i & 31) << 2;
    f16x4 h = {s_t[(c4    ) * 68 + p],
               s_t[(c4 + 1) * 68 + p],
               s_t[(c4 + 2) * 68 + p],
               s_t[(c4 + 3) * 68 + p]};
    *(f16x4*)&xtb[(size_t)(pos0 + p) * 128 + c4] = h;
  }
}

// ---------------- fused: LDS x-window + offset conv + bilinear table + DCN main loop ----------------
// One block per (b, ho), XCD = batch. The 7-row x-window [ho-3, ho+3] is staged
// ONCE into LDS with coalesced loads; all bilinear corner reads and phase-1 im2col
// taps become ds_read_b128 (off the vector-memory/TA path, which R2/R4/R5 showed
// to be the throughput limit: time invariant to barrier schedule AND L2 hit rate).
// Pixel-internal XOR swizzle (q^(x&3), c4bit^((x>>2)&1)) spreads the 64-lane
// scattered reads across banks (~b128 floor).
__global__ __launch_bounds__(256) void fused_dcn_kernel(const f16* __restrict__ xt,
                                                        const f16* __restrict__ wsA,
                                                        const f16* __restrict__ wsB,
                                                        const float* __restrict__ b_off,
                                                        const float* __restrict__ b_def,
                                                        float* __restrict__ out) {
  extern __shared__ __align__(16) char smem[];
  char*   xwin  = smem;
  uint4*  s_ofs = (uint4*)(smem + OFS_OFF);
  float4* s_wt  = (float4*)(smem + WT_OFF);
  float*  s_off = (float*)(smem + AOFF_OFF);   // alive phases 1-2
  f16*    s_a   = (f16*)(smem + AOFF_OFF);     // alive phase 3 ([2][4096])

  const int t = threadIdx.x;
  const int b = blockIdx.x & 7, ho = blockIdx.x >> 3;   // XCD = batch
  const int lane = t & 63, wid = t >> 6;
  const int q = lane >> 4, li = lane & 15;
  const int px = (wid << 4) + li;
  const char* xtb = (const char*)xt + ((size_t)b << 20);

  const int y_lo = (ho > 3) ? ho - 3 : 0;
  const int y_hi = (ho < 60) ? ho + 3 : 63;

  // ---- phase 0: stage x-window rows [y_lo, y_hi] into LDS (coalesced, swizzled) ----
  {
    const int nunits = (y_hi - y_lo + 1) << 10;   // 16B units: rows*64px*16
    for (int u = t; u < nunits; u += 256) {
      const int row = u >> 10, rem = u & 1023;
      const int xx = rem >> 4, s = rem & 15;
      const int qq = s & 3, cc4 = s >> 2;
      const uint4 v = *(const uint4*)(xtb + ((((y_lo + row) * 64 + xx) << 8) + (cc4 << 6) + (qq << 4)));
      const int s1 = xx & 3, s2 = (xx >> 2) & 1;
      *(uint4*)(xwin + (((row * 64 + xx) << 8) + ((qq ^ s1) << 4) + ((cc4 ^ s2) << 6))) = v;
    }
  }
  __syncthreads();   // window ready

  // ---- phase 1: offset conv, M=32 (27 live rows), taps read from LDS window ----
  {
    f32x4 acc0 = {0.f, 0.f, 0.f, 0.f}, acc1 = {0.f, 0.f, 0.f, 0.f};
    #pragma unroll
    for (int k = 0; k < 9; ++k) {
      const int ky = k / 3, kx = k - ky * 3;
      const int y = ho + ky - 1;
      const int xx = px + kx - 1;
      const bool valid = ((unsigned)y < 64u) && ((unsigned)xx < 64u);
      const int yc = min(max(y, y_lo), y_hi);
      const int xc = min(max(xx, 0), 63);
      const int s1 = xc & 3, s2 = (xc >> 2) & 1;
      const int base = (((yc - y_lo) * 64 + xc) << 8) + ((q ^ s1) << 4);
      #pragma unroll
      for (int c4 = 0; c4 < 4; ++c4) {
        union { uint4 u; f16x8 v; } bu;
        bu.u = *(const uint4*)(xwin + base + ((c4 ^ s2) << 6));
        if (!valid) { bu.u.x = 0u; bu.u.y = 0u; bu.u.z = 0u; bu.u.w = 0u; }
        const int ch = k * 4 + c4;
        f16x8 a0 = *(const f16x8*)&wsA[(ch * 2    ) * 512 + lane * 8];
        f16x8 a1 = *(const f16x8*)&wsA[(ch * 2 + 1) * 512 + lane * 8];
        acc0 = __builtin_amdgcn_mfma_f32_16x16x32_f16(a0, bu.v, acc0, 0, 0, 0);
        acc1 = __builtin_amdgcn_mfma_f32_16x16x32_f16(a1, bu.v, acc1, 0, 0, 0);
      }
    }
    #pragma unroll
    for (int mt = 0; mt < 2; ++mt) {
      f32x4 a = mt ? acc1 : acc0;
      #pragma unroll
      for (int r = 0; r < 4; ++r) {
        int oc = mt * 16 + q * 4 + r;
        if (oc < 27) {
          float v = a[r] + b_off[oc];
          if (oc >= 18) v = 1.0f / (1.0f + __expf(-v));
          s_off[oc * 65 + px] = v;
        }
      }
    }
  }
  __syncthreads();   // offset row ready in LDS

  // ---- phase 2: bilinear table (packed window-relative corner descriptors + weights) ----
  for (int f = t; f < 576; f += 256) {
    int k = f >> 6, p = f & 63;
    int ky = k / 3, kx = k - ky * 3;
    float oy = s_off[(2 * k    ) * 65 + p];
    float ox = s_off[(2 * k + 1) * 65 + p];
    float m  = s_off[(18 + k   ) * 65 + p];
    float py  = oy + (float)(ho + ky - 1);
    float pxf = ox + (float)(p + kx - 1);
    float y0f = floorf(py), x0f = floorf(pxf);
    float wy = py - y0f, wx = pxf - x0f;
    int y0 = (int)y0f, x0 = (int)x0f;
    int y1 = y0 + 1, x1 = x0 + 1;
    bool y0v = (unsigned)y0 < 64u, y1v = (unsigned)y1 < 64u;
    bool x0v = (unsigned)x0 < 64u, x1v = (unsigned)x1 < 64u;
    int y0a = min(max(y0, y_lo), y_hi), y1a = min(max(y1, y_lo), y_hi);
    int x0c = min(max(x0, 0), 63), x1c = min(max(x1, 0), 63);
    unsigned k00 = ((unsigned)(((y0a - y_lo) * 64 + x0c) << 8)) | ((unsigned)(x0c & 3) << 20) | ((unsigned)((x0c >> 2) & 1) << 22);
    unsigned k01 = ((unsigned)(((y0a - y_lo) * 64 + x1c) << 8)) | ((unsigned)(x1c & 3) << 20) | ((unsigned)((x1c >> 2) & 1) << 22);
    unsigned k10 = ((unsigned)(((y1a - y_lo) * 64 + x0c) << 8)) | ((unsigned)(x0c & 3) << 20) | ((unsigned)((x0c >> 2) & 1) << 22);
    unsigned k11 = ((unsigned)(((y1a - y_lo) * 64 + x1c) << 8)) | ((unsigned)(x1c & 3) << 20) | ((unsigned)((x1c >> 2) & 1) << 22);
    uint4 o4; o4.x = k00; o4.y = k01; o4.z = k10; o4.w = k11;
    float4 w4;
    w4.x = (y0v && x0v) ? (1.f - wy) * (1.f - wx) * m : 0.f;
    w4.y = (y0v && x1v) ? (1.f - wy) * wx         * m : 0.f;
    w4.z = (y1v && x0v) ? wy         * (1.f - wx) * m : 0.f;
    w4.w = (y1v && x1v) ? wy         * wx         * m : 0.f;
    s_ofs[f] = o4;
    s_wt[f]  = w4;
  }
  __syncthreads();   // table ready; s_off dead -> s_a region reusable

  // ---- phase 3: LDS-gather main loop (A dbuf via global_load_lds, corners via ds_read) ----
  f32x4 acc[8];
  #pragma unroll
  for (int mt = 0; mt < 8; ++mt) acc[mt] = (f32x4){0.f, 0.f, 0.f, 0.f};

  typedef union { uint4 u; f16x2 h[4]; } AU;
  AU Gc[4], Gn[4];

  // stage A(0) into s_a buf 0; prefetch chunk-0 corners from the window
  {
    const int seg = wid * 2;
    gload_lds16(wsB + seg * 512 + lane * 8,       s_a + seg * 512);
    gload_lds16(wsB + (seg + 1) * 512 + lane * 8, s_a + (seg + 1) * 512);
    const uint4 w = s_ofs[px];
    Gc[0].u = *(const uint4*)(xwin + CORNER_ADDR(w.x, 0));
    Gc[1].u = *(const uint4*)(xwin + CORNER_ADDR(w.y, 0));
    Gc[2].u = *(const uint4*)(xwin + CORNER_ADDR(w.z, 0));
    Gc[3].u = *(const uint4*)(xwin + CORNER_ADDR(w.w, 0));
  }
  asm volatile("s_waitcnt vmcnt(0)" ::: "memory");   // A(0) landed
  __builtin_amdgcn_s_barrier();

  #pragma unroll 1
  for (int ch = 0; ch < 36; ++ch) {
    const int k = ch >> 2;
    // stage A(ch+1) into the other buffer; prefetch next chunk's corners (LDS)
    if (ch < 35) {
      const int nb = (ch + 1) & 1;
      const int seg = wid * 2;
      const f16* src = wsB + (ch + 1) * 4096;
      gload_lds16(src + seg * 512 + lane * 8,       s_a + nb * 4096 + seg * 512);
      gload_lds16(src + (seg + 1) * 512 + lane * 8, s_a + nb * 4096 + (seg + 1) * 512);
      const int kn = (ch + 1) >> 2, c4n = (ch + 1) & 3;
      const uint4 w = s_ofs[kn * 64 + px];
      Gn[0].u = *(const uint4*)(xwin + CORNER_ADDR(w.x, c4n));
      Gn[1].u = *(const uint4*)(xwin + CORNER_ADDR(w.y, c4n));
      Gn[2].u = *(const uint4*)(xwin + CORNER_ADDR(w.z, c4n));
      Gn[3].u = *(const uint4*)(xwin + CORNER_ADDR(w.w, c4n));
    }
    // pack current chunk's B fragment
    const float4 w4 = s_wt[k * 64 + px];
    const f16 h0 = (f16)w4.x, h1 = (f16)w4.y, h2 = (f16)w4.z, h3 = (f16)w4.w;
    const f16x2 wp0 = {h0, h0}, wp1 = {h1, h1}, wp2 = {h2, h2}, wp3 = {h3, h3};
    union { f16x2 h[4]; f16x8 v; } bf;
    #pragma unroll
    for (int i = 0; i < 4; ++i) {
      f16x2 s = Gc[0].h[i] * wp0;
      s = s + Gc[1].h[i] * wp1;
      s = s + Gc[2].h[i] * wp2;
      s = s + Gc[3].h[i] * wp3;
      bf.h[i] = s;
    }
    const f16* ab = s_a + (ch & 1) * 4096;
    #pragma unroll
    for (int mt = 0; mt < 8; ++mt) {
      f16x8 a = *(const f16x8*)&ab[(mt * 64 + lane) * 8];
      acc[mt] = __builtin_amdgcn_mfma_f32_16x16x32_f16(a, bf.v, acc[mt], 0, 0, 0);
    }
    __syncthreads();   // drain A staging + protect dbuf swap
    if (ch < 35) { Gc[0] = Gn[0]; Gc[1] = Gn[1]; Gc[2] = Gn[2]; Gc[3] = Gn[3]; }
  }

  float* o = out + (size_t)b * 128 * 4096 + ho * 64 + px;
  #pragma unroll
  for (int mt = 0; mt < 8; ++mt) {
    #pragma unroll
    for (int r = 0; r < 4; ++r) {
      int oc = mt * 16 + q * 4 + r;
      o[oc * 4096] = acc[mt][r] + b_def[oc];
    }
  }
}

extern "C" void kernel_launch(void* const* d_in, const int* in_sizes, int n_in,
                              void* d_out, int out_size, void* d_ws, size_t ws_size,
                              hipStream_t stream) {
  const float* x     = (const float*)d_in[0];
  const float* w_off = (const float*)d_in[1];
  const float* b_off = (const float*)d_in[2];
  const float* w_def = (const float*)d_in[3];
  const float* b_def = (const float*)d_in[4];
  float* out = (float*)d_out;

  f16* wsA = (f16*)d_ws;
  f16* wsB = (f16*)((char*)d_ws + OFF_WSB);
  f16* xt  = (f16*)((char*)d_ws + OFF_XT);

  static int smem_opted = 0;
  if (!smem_opted) {
    hipFuncSetAttribute((const void*)fused_dcn_kernel,
                        hipFuncAttributeMaxDynamicSharedMemorySize, SMEM_BYTES);
    smem_opted = 1;
  }

  prep_transpose_kernel<<<dim3(PREP_BLOCKS + NBATCH * 64), dim3(256), 0, stream>>>(
      w_off, w_def, wsA, wsB, x, xt);
  fused_dcn_kernel<<<dim3(NBATCH * 64), dim3(256), SMEM_BYTES, stream>>>(
      xt, wsA, wsB, b_off, b_def, out);
}